// Round 8
// baseline (430.320 us; speedup 1.0000x reference)
//
#include <hip/hip_runtime.h>
#include <math.h>

#define BB 4
#define CC 64
#define OCC 64
#define HH 256
#define WW 256
#define HP 258
#define WP 258
#define NPIX (BB * HH * WW)          // 262144
#define CNT_F 262144.0f

typedef __attribute__((ext_vector_type(8))) __bf16 bf16x8;
typedef __attribute__((ext_vector_type(4))) float f32x4;

__device__ __forceinline__ float blo(unsigned u) {
    return __builtin_bit_cast(float, u << 16);
}
__device__ __forceinline__ float bhi(unsigned u) {
    return __builtin_bit_cast(float, u & 0xffff0000u);
}

// ---------------------------------------------------------------------------
// Kernel P (MERGED): pad_transpose (blocks 0..4095) + zero_border
// (4096..5123) + reorder_weights (5124..5339) + stats zero (5340).
// (unchanged)
// ---------------------------------------------------------------------------
__global__ __launch_bounds__(256) void prep(const float* __restrict__ x,
                                            __bf16* __restrict__ xt,
                                            const float* __restrict__ cw,
                                            const float* __restrict__ pw,
                                            __bf16* __restrict__ wtb,
                                            __bf16* __restrict__ pwb,
                                            float* __restrict__ stats) {
    int blk = blockIdx.x;
    int tid = threadIdx.x;
    if (blk < 4096) {
        // ---- pad+transpose interior ----
        int xchunk = blk & 3;
        int y = (blk >> 2) & 255;
        int b = blk >> 10;
        __shared__ float tile[64][65];
        int x0 = xchunk * 64;
        int col = tid & 63;
        int crow = tid >> 6;             // 0..3
        const float* xp = x + ((size_t)b * CC) * HH * WW + (size_t)y * WW + x0;
#pragma unroll
        for (int i = 0; i < 16; ++i) {
            int c = crow + i * 4;
            tile[c][col] = xp[(size_t)c * HH * WW + col];
        }
        __syncthreads();
        __bf16* op = xt + (((size_t)b * HP + (y + 1)) * WP + (x0 + 1)) * CC;
#pragma unroll
        for (int i = 0; i < 16; ++i) {
            int xl = crow + i * 4;
            op[(size_t)xl * CC + col] = (__bf16)tile[col][xl];
        }
    } else if (blk < 5124) {
        // ---- zero border ----
        int i = (blk - 4096) * 256 + tid;
        const int total = BB * 1028 * CC;
        if (i >= total) return;
        int c = i & 63;
        int p = (i >> 6) % 1028;
        int b = (i >> 6) / 1028;
        int yp, xp;
        if (p < 258)      { yp = 0;           xp = p; }
        else if (p < 516) { yp = 257;         xp = p - 258; }
        else if (p < 772) { yp = p - 516 + 1; xp = 0; }
        else              { yp = p - 772 + 1; xp = 257; }
        xt[(((size_t)b * HP + yp) * WP + xp) * CC + c] = (__bf16)0.0f;
    } else if (blk < 5340) {
        // ---- reorder weights ----
        int i = (blk - 5124) * 256 + tid;
        if (i < 36864) {                          // wtb[oc*576 + n*64 + c]
            int c = i & 63;
            int n = (i >> 6) % 9;
            int oc = i / 576;
            wtb[i] = (__bf16)cw[((size_t)oc * CC + c) * 9 + n];
        } else {
            int j = i - 36864;
            if (j >= 18432) return;               // pwb: 32 x 576
            int c = j & 63;
            int n = (j >> 6) % 9;
            int oc = j / 576;
            pwb[j] = (__bf16)(oc < 18 ? pw[((size_t)oc * CC + c) * 9 + n] : 0.0f);
        }
    } else {
        // ---- zero stats ----
        if (tid < 128) stats[tid] = 0.0f;
    }
}

// ---------------------------------------------------------------------------
// Kernel C (FUSED): offset conv + deformable sampling + MFMA, 16 px/block.
// Round-8 changes:
//  * phase S (LDS strip staging) REMOVED: phase O reads A-fragments
//    directly from global xt (L2-hot; B already came from global). One
//    barrier instead of two; staged-copy round-trip off the critical path.
//    Same bf16 bits + same MFMA order -> offsets bit-identical.
//  * stats fused as CONTENTION-FREE per-block partials: 4-lane shfl
//    reduce -> 128 coalesced plain stores per block (8.4 MB total).
//    (Round 6's failure was 2.1M same-address atomics; this has zero
//    atomics.) stats_reduce kernel finishes the job.
// Phases 0'/1/2 unchanged (round-3 proven structure).
// LDS: sA 18432 + offp 2304 = 20736 B -> 7 blocks/CU.
// ---------------------------------------------------------------------------
__global__ __launch_bounds__(256, 7) void deform_fused(const __bf16* __restrict__ xt,
                                                       const __bf16* __restrict__ pwb,
                                                       const float* __restrict__ pb,
                                                       const __bf16* __restrict__ wtb,
                                                       float* __restrict__ out,
                                                       float* __restrict__ partials) {
    int phys = blockIdx.x;                    // 16384
    int blk = (phys & 7) * 2048 + (phys >> 3);   // XCD band swizzle
    int xh = blk & 15;
    int y  = (blk >> 4) & 255;
    int b  = blk >> 12;
    int x0 = xh * 16;
    int tid = threadIdx.x;
    int wave = tid >> 6, lane = tid & 63;
    int chp = lane & 31, half = lane >> 5;

    __shared__ __attribute__((aligned(16))) char smem[20736];
    char* sAb = smem;                                   // sA[16][576] = 18432 B
    float* offp = (float*)(smem + 18432);               // [2][16][18] f32 = 2304 B

    const char* xb = (const char*)xt + (size_t)b * HP * WP * CC * 2;

    // ---- phase O: offset conv MFMA, 4 waves (oc-half x K-half),
    //      A-fragments straight from global xt ----
    {
        int nh = wave & 1;                        // oc half
        int kh = wave >> 1;                       // K half (taps 0..4 / 5..8)
        int m = lane & 15, q = lane >> 4;
        f32x4 acc = {0.0f, 0.0f, 0.0f, 0.0f};
        const __bf16* bp = pwb + (size_t)(nh * 16 + m) * 576 + q * 8;
        if (kh == 0) {
#pragma unroll
            for (int n = 0; n < 5; ++n) {
                int dy = n / 3, dx = n - dy * 3;
                const char* ap = xb + (size_t)((y + dy) * WP + (x0 + m + dx)) * (CC * 2) + q * 16;
                bf16x8 a0 = *(const bf16x8*)(ap);
                bf16x8 a1 = *(const bf16x8*)(ap + 64);
                bf16x8 bv0 = *(const bf16x8*)(bp + n * 64);
                bf16x8 bv1 = *(const bf16x8*)(bp + n * 64 + 32);
                acc = __builtin_amdgcn_mfma_f32_16x16x32_bf16(a0, bv0, acc, 0, 0, 0);
                acc = __builtin_amdgcn_mfma_f32_16x16x32_bf16(a1, bv1, acc, 0, 0, 0);
            }
        } else {
#pragma unroll
            for (int n = 5; n < 9; ++n) {
                int dy = n / 3, dx = n - dy * 3;
                const char* ap = xb + (size_t)((y + dy) * WP + (x0 + m + dx)) * (CC * 2) + q * 16;
                bf16x8 a0 = *(const bf16x8*)(ap);
                bf16x8 a1 = *(const bf16x8*)(ap + 64);
                bf16x8 bv0 = *(const bf16x8*)(bp + n * 64);
                bf16x8 bv1 = *(const bf16x8*)(bp + n * 64 + 32);
                acc = __builtin_amdgcn_mfma_f32_16x16x32_bf16(a0, bv0, acc, 0, 0, 0);
                acc = __builtin_amdgcn_mfma_f32_16x16x32_bf16(a1, bv1, acc, 0, 0, 0);
            }
        }
        int oc = nh * 16 + m;
        if (oc < 18) {
            float bias = (kh == 0) ? pb[oc] : 0.0f;   // bias once (kh=0 half)
            float* obf = offp + kh * 288;
#pragma unroll
            for (int r = 0; r < 4; ++r)
                obf[(q * 4 + r) * 18 + oc] = acc[r] + bias;  // px = q*4+r
        }
    }
    __syncthreads();

    // ---- phase 0': per-wave coords in registers (lanes 0..35 = 36 tasks) ----
    float g0 = 0.0f, g1 = 0.0f, g2 = 0.0f, g3 = 0.0f;
    int c0 = 0, c1 = 0, c2 = 0, c3 = 0;
    if (lane < 36) {
        int t = wave * 36 + lane;
        int n = t >> 4, p = t & 15;
        float offx = offp[p * 18 + n]     + offp[288 + p * 18 + n];
        float offy = offp[p * 18 + n + 9] + offp[288 + p * 18 + n + 9];
        float px = offx + (float)(y + 1) + (float)(n / 3 - 1);
        float py = offy + (float)(x0 + p + 1) + (float)(n % 3 - 1);
        float fx = floorf(px), fy = floorf(py);
        float pxc = fminf(fmaxf(px, 0.0f), 257.0f);
        float pyc = fminf(fmaxf(py, 0.0f), 257.0f);
        int ltx = (int)fminf(fmaxf(fx, 0.0f), 257.0f);
        int lty = (int)fminf(fmaxf(fy, 0.0f), 257.0f);
        int rbx = (int)fminf(fmaxf(fx + 1.0f, 0.0f), 257.0f);
        int rby = (int)fminf(fmaxf(fy + 1.0f, 0.0f), 257.0f);
        float dxl = 1.0f + ((float)ltx - pxc);
        float dxr = 1.0f - ((float)rbx - pxc);
        float dyl = 1.0f + ((float)lty - pyc);
        float dyr = 1.0f - ((float)rby - pyc);
        g0 = dxl * dyl;                            // lt
        g1 = dxr * dyr;                            // rb
        g2 = dxl * dyr;                            // lb (ltx, rby)
        g3 = dxr * dyl;                            // rt (rbx, lty)
        c0 = ((ltx * WP + lty) * CC) * 2;          // byte offsets
        c1 = ((rbx * WP + rby) * CC) * 2;
        c2 = ((ltx * WP + rby) * CC) * 2;
        c3 = ((rbx * WP + lty) * CC) * 2;
    }

    // ---- phase 1: gather+blend, 2 ch/lane, 2 tasks/round, shfl coords ----
    {
        const char* xbl = xb + (size_t)chp * 4;
#pragma unroll 3
        for (int r = 0; r < 18; ++r) {
            int src = r * 2 + half;                // 0..35
            float gx = __shfl(g0, src, 64);
            float gy = __shfl(g1, src, 64);
            float gz = __shfl(g2, src, 64);
            float gw = __shfl(g3, src, 64);
            int vx = __shfl(c0, src, 64);
            int vy = __shfl(c1, src, 64);
            int vz = __shfl(c2, src, 64);
            int vw = __shfl(c3, src, 64);
            unsigned d0 = *(const unsigned*)(xbl + vx);
            unsigned d1 = *(const unsigned*)(xbl + vy);
            unsigned d2 = *(const unsigned*)(xbl + vz);
            unsigned d3 = *(const unsigned*)(xbl + vw);
            float lo = gx * blo(d0) + gy * blo(d1) + gz * blo(d2) + gw * blo(d3);
            float hi = gx * bhi(d0) + gy * bhi(d1) + gz * bhi(d2) + gw * bhi(d3);
            __bf16 rlo = (__bf16)lo, rhi = (__bf16)hi;
            ushort2 rv;
            rv.x = __builtin_bit_cast(unsigned short, rlo);
            rv.y = __builtin_bit_cast(unsigned short, rhi);
            int t = wave * 36 + src;
            int n = t >> 4, p = t & 15;
            unsigned bo = (unsigned)p * 1152u + (unsigned)n * 128u + (unsigned)chp * 4u;
            bo ^= (unsigned)((p & 7) << 4);        // swizzle
            *(ushort2*)(sAb + bo) = rv;
        }
    }
    __syncthreads();

    // ---- phase 2: MFMA over K=576; wave -> 16 px x oc[wave*16..+16) ----
    int m = lane & 15, q = lane >> 4;
    f32x4 acc = {0.0f, 0.0f, 0.0f, 0.0f};
    {
        unsigned rowb = (unsigned)m * 1152u;
        unsigned key = (unsigned)((m & 7) << 4);
        const __bf16* bp = wtb + (size_t)(wave * 16 + m) * 576 + q * 8;
        __builtin_amdgcn_s_setprio(1);
#pragma unroll
        for (int k0 = 0; k0 < 576; k0 += 32) {
            unsigned bo = rowb + (((unsigned)(k0 * 2 + q * 16)) ^ key);
            bf16x8 a  = *(const bf16x8*)(sAb + bo);
            bf16x8 bv = *(const bf16x8*)(bp + k0);
            acc = __builtin_amdgcn_mfma_f32_16x16x32_bf16(a, bv, acc, 0, 0, 0);
        }
        __builtin_amdgcn_s_setprio(0);
    }

    // ---- direct store: px = q*4 + r (consecutive) -> one float4 per lane ----
    int oc = wave * 16 + m;
    float* ob = out + (((size_t)b * OCC + oc) * HH + y) * WW + x0 + q * 4;
    float4 v;
    v.x = acc[0]; v.y = acc[1]; v.z = acc[2]; v.w = acc[3];
    *(float4*)ob = v;

    // ---- stats partials: 4-lane (q) shfl reduce -> plain coalesced stores ----
    {
        float s  = acc[0] + acc[1] + acc[2] + acc[3];
        float sq = acc[0] * acc[0] + acc[1] * acc[1]
                 + acc[2] * acc[2] + acc[3] * acc[3];
        s  += __shfl_xor(s, 16, 64);
        sq += __shfl_xor(sq, 16, 64);
        s  += __shfl_xor(s, 32, 64);
        sq += __shfl_xor(sq, 32, 64);
        if (q == 0) {                              // lanes 0..15, m = lane
            float* pp = partials + (size_t)phys * 128;
            pp[oc] = s;
            pp[64 + oc] = sq;
        }
    }
}

// ---------------------------------------------------------------------------
// Kernel R: reduce partials[16384][128] -> stats[128]. Fully coalesced:
// 64 blocks x 256 rows; threads (rg=tid>>5, cg=tid&31) read float4 at
// row=blk*256+rg+8r, cols cg*4..+3; LDS transpose; 128 atomics/block.
// ---------------------------------------------------------------------------
__global__ __launch_bounds__(256) void stats_reduce(const float* __restrict__ partials,
                                                    float* __restrict__ stats) {
    __shared__ float sacc[8][128];
    int tid = threadIdx.x;
    int cg = tid & 31;          // col quad
    int rg = tid >> 5;          // row group 0..7
    float a0 = 0.0f, a1 = 0.0f, a2 = 0.0f, a3 = 0.0f;
    const float* base = partials + ((size_t)blockIdx.x * 256 + rg) * 128 + cg * 4;
#pragma unroll 4
    for (int r = 0; r < 32; ++r) {
        float4 v = *(const float4*)(base + (size_t)r * 8 * 128);
        a0 += v.x; a1 += v.y; a2 += v.z; a3 += v.w;
    }
    sacc[rg][cg * 4 + 0] = a0;
    sacc[rg][cg * 4 + 1] = a1;
    sacc[rg][cg * 4 + 2] = a2;
    sacc[rg][cg * 4 + 3] = a3;
    __syncthreads();
    if (tid < 128) {
        float s = 0.0f;
#pragma unroll
        for (int g = 0; g < 8; ++g) s += sacc[g][tid];
        atomicAdd(&stats[tid], s);
    }
}

// ---------------------------------------------------------------------------
// Kernel E: BN (batch stats) + LeakyReLU(0.1), in-place on out. (unchanged)
// ---------------------------------------------------------------------------
__global__ __launch_bounds__(256) void bn_leaky(float* __restrict__ out,
                                                const float* __restrict__ stats,
                                                const float* __restrict__ gamma,
                                                const float* __restrict__ beta) {
    int i = blockIdx.x * 256 + threadIdx.x;      // float4 index
    int oc = (i >> 14) & 63;
    float mean = stats[oc] * (1.0f / CNT_F);
    float var = stats[64 + oc] * (1.0f / CNT_F) - mean * mean;
    float scale = gamma[oc] * rsqrtf(var + 1e-5f);
    float shift = beta[oc] - mean * scale;
    float4* o4 = (float4*)out;
    float4 v = o4[i];
    v.x = v.x * scale + shift; v.x = v.x > 0.0f ? v.x : 0.1f * v.x;
    v.y = v.y * scale + shift; v.y = v.y > 0.0f ? v.y : 0.1f * v.y;
    v.z = v.z * scale + shift; v.z = v.z > 0.0f ? v.z : 0.1f * v.z;
    v.w = v.w * scale + shift; v.w = v.w > 0.0f ? v.w : 0.1f * v.w;
    o4[i] = v;
}

// ---------------------------------------------------------------------------
extern "C" void kernel_launch(void* const* d_in, const int* in_sizes, int n_in,
                              void* d_out, int out_size, void* d_ws, size_t ws_size,
                              hipStream_t stream) {
    (void)in_sizes; (void)n_in; (void)out_size; (void)ws_size;
    const float* x     = (const float*)d_in[0];
    const float* pw    = (const float*)d_in[1];
    const float* pb    = (const float*)d_in[2];
    const float* cw    = (const float*)d_in[3];
    const float* gamma = (const float*)d_in[4];
    const float* beta  = (const float*)d_in[5];
    float* out = (float*)d_out;
    char* ws = (char*)d_ws;

    __bf16* xtb  = (__bf16*)ws;                       // 34,080,768 B
    float* partials = (float*)(ws + 34080768);        // 8,388,608 B (old off region)
    __bf16* wtb  = (__bf16*)(ws + 34080768 + 18874368);            // 73,728 B
    __bf16* pwb  = (__bf16*)(ws + 34080768 + 18874368 + 73728);    // 36,864 B
    float*  stats = (float*)(ws + 34080768 + 18874368 + 73728 + 36864);

    prep<<<5341, 256, 0, stream>>>(x, xtb, cw, pw, wtb, pwb, stats);
    deform_fused<<<16384, 256, 0, stream>>>(xtb, pwb, pb, wtb, out, partials);
    stats_reduce<<<64, 256, 0, stream>>>(partials, stats);
    bn_leaky<<<NPIX * OCC / 4 / 256, 256, 0, stream>>>(out, stats, gamma, beta);
}

// Round 9
// 371.529 us; speedup vs baseline: 1.1582x; 1.1582x over previous
//
#include <hip/hip_runtime.h>
#include <math.h>

#define BB 4
#define CC 64
#define OCC 64
#define HH 256
#define WW 256
#define HP 258
#define WP 258
#define NPIX (BB * HH * WW)          // 262144
#define CNT_F 262144.0f

typedef __attribute__((ext_vector_type(8))) __bf16 bf16x8;
typedef __attribute__((ext_vector_type(4))) float f32x4;

__device__ __forceinline__ float blo(unsigned u) {
    return __builtin_bit_cast(float, u << 16);
}
__device__ __forceinline__ float bhi(unsigned u) {
    return __builtin_bit_cast(float, u & 0xffff0000u);
}

// ---------------------------------------------------------------------------
// Kernel P (MERGED): pad_transpose (blocks 0..4095) + zero_border
// (4096..5123) + reorder_weights (5124..5339) + stats zero (5340).
// (unchanged)
// ---------------------------------------------------------------------------
__global__ __launch_bounds__(256) void prep(const float* __restrict__ x,
                                            __bf16* __restrict__ xt,
                                            const float* __restrict__ cw,
                                            const float* __restrict__ pw,
                                            __bf16* __restrict__ wtb,
                                            __bf16* __restrict__ pwb,
                                            float* __restrict__ stats) {
    int blk = blockIdx.x;
    int tid = threadIdx.x;
    if (blk < 4096) {
        // ---- pad+transpose interior ----
        int xchunk = blk & 3;
        int y = (blk >> 2) & 255;
        int b = blk >> 10;
        __shared__ float tile[64][65];
        int x0 = xchunk * 64;
        int col = tid & 63;
        int crow = tid >> 6;             // 0..3
        const float* xp = x + ((size_t)b * CC) * HH * WW + (size_t)y * WW + x0;
#pragma unroll
        for (int i = 0; i < 16; ++i) {
            int c = crow + i * 4;
            tile[c][col] = xp[(size_t)c * HH * WW + col];
        }
        __syncthreads();
        __bf16* op = xt + (((size_t)b * HP + (y + 1)) * WP + (x0 + 1)) * CC;
#pragma unroll
        for (int i = 0; i < 16; ++i) {
            int xl = crow + i * 4;
            op[(size_t)xl * CC + col] = (__bf16)tile[col][xl];
        }
    } else if (blk < 5124) {
        // ---- zero border ----
        int i = (blk - 4096) * 256 + tid;
        const int total = BB * 1028 * CC;
        if (i >= total) return;
        int c = i & 63;
        int p = (i >> 6) % 1028;
        int b = (i >> 6) / 1028;
        int yp, xp;
        if (p < 258)      { yp = 0;           xp = p; }
        else if (p < 516) { yp = 257;         xp = p - 258; }
        else if (p < 772) { yp = p - 516 + 1; xp = 0; }
        else              { yp = p - 772 + 1; xp = 257; }
        xt[(((size_t)b * HP + yp) * WP + xp) * CC + c] = (__bf16)0.0f;
    } else if (blk < 5340) {
        // ---- reorder weights ----
        int i = (blk - 5124) * 256 + tid;
        if (i < 36864) {                          // wtb[oc*576 + n*64 + c]
            int c = i & 63;
            int n = (i >> 6) % 9;
            int oc = i / 576;
            wtb[i] = (__bf16)cw[((size_t)oc * CC + c) * 9 + n];
        } else {
            int j = i - 36864;
            if (j >= 18432) return;               // pwb: 32 x 576
            int c = j & 63;
            int n = (j >> 6) % 9;
            int oc = j / 576;
            pwb[j] = (__bf16)(oc < 18 ? pw[((size_t)oc * CC + c) * 9 + n] : 0.0f);
        }
    } else {
        // ---- zero stats ----
        if (tid < 128) stats[tid] = 0.0f;
    }
}

// ---------------------------------------------------------------------------
// Kernel C (FUSED): offset conv + deformable sampling + MFMA, 16 px/block.
// Round-9: composition of the two independently-measured wins:
//  * phase S/O = round-7 exact (dwordx4 LDS staging + 4-wave K-split;
//    round-8's direct-global phase O cost +58 us -> reverted).
//  * stats partials epilogue = round-8 exact (4-lane shfl reduce -> plain
//    coalesced stores; replaced the ~58 us stats_kernel re-read).
// Phases 0'/1/2 unchanged (round-3 proven structure).
// LDS: sA 18432 + offp 2304 = 20736 B -> 7 blocks/CU.
// ---------------------------------------------------------------------------
__global__ __launch_bounds__(256, 7) void deform_fused(const __bf16* __restrict__ xt,
                                                       const __bf16* __restrict__ pwb,
                                                       const float* __restrict__ pb,
                                                       const __bf16* __restrict__ wtb,
                                                       float* __restrict__ out,
                                                       float* __restrict__ partials) {
    int phys = blockIdx.x;                    // 16384
    int blk = (phys & 7) * 2048 + (phys >> 3);   // XCD band swizzle
    int xh = blk & 15;
    int y  = (blk >> 4) & 255;
    int b  = blk >> 12;
    int x0 = xh * 16;
    int tid = threadIdx.x;
    int wave = tid >> 6, lane = tid & 63;
    int chp = lane & 31, half = lane >> 5;

    __shared__ __attribute__((aligned(16))) char smem[20736];
    __bf16 (*sS)[18][72] = (__bf16 (*)[18][72])smem;   // 7776 B, aliases sA
    char* sAb = smem;                                   // sA[16][576] = 18432 B
    float* offp = (float*)(smem + 18432);               // [2][16][18] f32 = 2304 B

    // ---- phase S: stage strip rows y..y+2, cols x0..x0+17, dwordx4 ----
    {
        const char* base = (const char*)xt + (size_t)b * HP * WP * CC * 2;
        for (int t = tid; t < 432; t += 256) {       // 54 pos x 8 chunks(16B)
            int pos = t >> 3, c8 = t & 7;
            int r = pos / 18, j = pos - r * 18;
            uint4 d = *(const uint4*)(base
                + (size_t)((y + r) * WP + (x0 + j)) * (CC * 2) + c8 * 16);
            *(uint4*)&sS[r][j][c8 * 8] = d;
        }
    }
    __syncthreads();

    // ---- phase O: offset conv MFMA, 4 waves (oc-half x K-half) ----
    {
        int nh = wave & 1;                        // oc half
        int kh = wave >> 1;                       // K half (taps 0..4 / 5..8)
        int m = lane & 15, q = lane >> 4;
        f32x4 acc = {0.0f, 0.0f, 0.0f, 0.0f};
        const __bf16* bp = pwb + (size_t)(nh * 16 + m) * 576 + q * 8;
        if (kh == 0) {
#pragma unroll
            for (int n = 0; n < 5; ++n) {
                int dy = n / 3, dx = n - dy * 3;
                const __bf16* abase = &sS[dy][m + dx][q * 8];
#pragma unroll
                for (int h = 0; h < 2; ++h) {
                    bf16x8 a  = *(const bf16x8*)(abase + h * 32);
                    bf16x8 bv = *(const bf16x8*)(bp + n * 64 + h * 32);
                    acc = __builtin_amdgcn_mfma_f32_16x16x32_bf16(a, bv, acc, 0, 0, 0);
                }
            }
        } else {
#pragma unroll
            for (int n = 5; n < 9; ++n) {
                int dy = n / 3, dx = n - dy * 3;
                const __bf16* abase = &sS[dy][m + dx][q * 8];
#pragma unroll
                for (int h = 0; h < 2; ++h) {
                    bf16x8 a  = *(const bf16x8*)(abase + h * 32);
                    bf16x8 bv = *(const bf16x8*)(bp + n * 64 + h * 32);
                    acc = __builtin_amdgcn_mfma_f32_16x16x32_bf16(a, bv, acc, 0, 0, 0);
                }
            }
        }
        int oc = nh * 16 + m;
        if (oc < 18) {
            float bias = (kh == 0) ? pb[oc] : 0.0f;   // bias once (kh=0 half)
            float* obf = offp + kh * 288;
#pragma unroll
            for (int r = 0; r < 4; ++r)
                obf[(q * 4 + r) * 18 + oc] = acc[r] + bias;  // px = q*4+r
        }
    }
    __syncthreads();

    // ---- phase 0': per-wave coords in registers (lanes 0..35 = 36 tasks) ----
    float g0 = 0.0f, g1 = 0.0f, g2 = 0.0f, g3 = 0.0f;
    int c0 = 0, c1 = 0, c2 = 0, c3 = 0;
    if (lane < 36) {
        int t = wave * 36 + lane;
        int n = t >> 4, p = t & 15;
        float offx = offp[p * 18 + n]     + offp[288 + p * 18 + n];
        float offy = offp[p * 18 + n + 9] + offp[288 + p * 18 + n + 9];
        float px = offx + (float)(y + 1) + (float)(n / 3 - 1);
        float py = offy + (float)(x0 + p + 1) + (float)(n % 3 - 1);
        float fx = floorf(px), fy = floorf(py);
        float pxc = fminf(fmaxf(px, 0.0f), 257.0f);
        float pyc = fminf(fmaxf(py, 0.0f), 257.0f);
        int ltx = (int)fminf(fmaxf(fx, 0.0f), 257.0f);
        int lty = (int)fminf(fmaxf(fy, 0.0f), 257.0f);
        int rbx = (int)fminf(fmaxf(fx + 1.0f, 0.0f), 257.0f);
        int rby = (int)fminf(fmaxf(fy + 1.0f, 0.0f), 257.0f);
        float dxl = 1.0f + ((float)ltx - pxc);
        float dxr = 1.0f - ((float)rbx - pxc);
        float dyl = 1.0f + ((float)lty - pyc);
        float dyr = 1.0f - ((float)rby - pyc);
        g0 = dxl * dyl;                            // lt
        g1 = dxr * dyr;                            // rb
        g2 = dxl * dyr;                            // lb (ltx, rby)
        g3 = dxr * dyl;                            // rt (rbx, lty)
        c0 = ((ltx * WP + lty) * CC) * 2;          // byte offsets
        c1 = ((rbx * WP + rby) * CC) * 2;
        c2 = ((ltx * WP + rby) * CC) * 2;
        c3 = ((rbx * WP + lty) * CC) * 2;
    }

    // ---- phase 1: gather+blend, 2 ch/lane, 2 tasks/round, shfl coords ----
    {
        const char* xbl = (const char*)xt + (size_t)b * HP * WP * CC * 2 + (size_t)chp * 4;
#pragma unroll 3
        for (int r = 0; r < 18; ++r) {
            int src = r * 2 + half;                // 0..35
            float gx = __shfl(g0, src, 64);
            float gy = __shfl(g1, src, 64);
            float gz = __shfl(g2, src, 64);
            float gw = __shfl(g3, src, 64);
            int vx = __shfl(c0, src, 64);
            int vy = __shfl(c1, src, 64);
            int vz = __shfl(c2, src, 64);
            int vw = __shfl(c3, src, 64);
            unsigned d0 = *(const unsigned*)(xbl + vx);
            unsigned d1 = *(const unsigned*)(xbl + vy);
            unsigned d2 = *(const unsigned*)(xbl + vz);
            unsigned d3 = *(const unsigned*)(xbl + vw);
            float lo = gx * blo(d0) + gy * blo(d1) + gz * blo(d2) + gw * blo(d3);
            float hi = gx * bhi(d0) + gy * bhi(d1) + gz * bhi(d2) + gw * bhi(d3);
            __bf16 rlo = (__bf16)lo, rhi = (__bf16)hi;
            ushort2 rv;
            rv.x = __builtin_bit_cast(unsigned short, rlo);
            rv.y = __builtin_bit_cast(unsigned short, rhi);
            int t = wave * 36 + src;
            int n = t >> 4, p = t & 15;
            unsigned bo = (unsigned)p * 1152u + (unsigned)n * 128u + (unsigned)chp * 4u;
            bo ^= (unsigned)((p & 7) << 4);        // swizzle
            *(ushort2*)(sAb + bo) = rv;
        }
    }
    __syncthreads();

    // ---- phase 2: MFMA over K=576; wave -> 16 px x oc[wave*16..+16) ----
    int m = lane & 15, q = lane >> 4;
    f32x4 acc = {0.0f, 0.0f, 0.0f, 0.0f};
    {
        unsigned rowb = (unsigned)m * 1152u;
        unsigned key = (unsigned)((m & 7) << 4);
        const __bf16* bp = wtb + (size_t)(wave * 16 + m) * 576 + q * 8;
        __builtin_amdgcn_s_setprio(1);
#pragma unroll
        for (int k0 = 0; k0 < 576; k0 += 32) {
            unsigned bo = rowb + (((unsigned)(k0 * 2 + q * 16)) ^ key);
            bf16x8 a  = *(const bf16x8*)(sAb + bo);
            bf16x8 bv = *(const bf16x8*)(bp + k0);
            acc = __builtin_amdgcn_mfma_f32_16x16x32_bf16(a, bv, acc, 0, 0, 0);
        }
        __builtin_amdgcn_s_setprio(0);
    }

    // ---- direct store: px = q*4 + r (consecutive) -> one float4 per lane ----
    int oc = wave * 16 + m;
    float* ob = out + (((size_t)b * OCC + oc) * HH + y) * WW + x0 + q * 4;
    float4 v;
    v.x = acc[0]; v.y = acc[1]; v.z = acc[2]; v.w = acc[3];
    *(float4*)ob = v;

    // ---- stats partials: 4-lane (q) shfl reduce -> plain coalesced stores ----
    {
        float s  = acc[0] + acc[1] + acc[2] + acc[3];
        float sq = acc[0] * acc[0] + acc[1] * acc[1]
                 + acc[2] * acc[2] + acc[3] * acc[3];
        s  += __shfl_xor(s, 16, 64);
        sq += __shfl_xor(sq, 16, 64);
        s  += __shfl_xor(s, 32, 64);
        sq += __shfl_xor(sq, 32, 64);
        if (q == 0) {                              // lanes 0..15, m = lane
            float* pp = partials + (size_t)phys * 128;
            pp[oc] = s;
            pp[64 + oc] = sq;
        }
    }
}

// ---------------------------------------------------------------------------
// Kernel R: reduce partials[16384][128] -> stats[128]. (round-8 exact)
// ---------------------------------------------------------------------------
__global__ __launch_bounds__(256) void stats_reduce(const float* __restrict__ partials,
                                                    float* __restrict__ stats) {
    __shared__ float sacc[8][128];
    int tid = threadIdx.x;
    int cg = tid & 31;          // col quad
    int rg = tid >> 5;          // row group 0..7
    float a0 = 0.0f, a1 = 0.0f, a2 = 0.0f, a3 = 0.0f;
    const float* base = partials + ((size_t)blockIdx.x * 256 + rg) * 128 + cg * 4;
#pragma unroll 4
    for (int r = 0; r < 32; ++r) {
        float4 v = *(const float4*)(base + (size_t)r * 8 * 128);
        a0 += v.x; a1 += v.y; a2 += v.z; a3 += v.w;
    }
    sacc[rg][cg * 4 + 0] = a0;
    sacc[rg][cg * 4 + 1] = a1;
    sacc[rg][cg * 4 + 2] = a2;
    sacc[rg][cg * 4 + 3] = a3;
    __syncthreads();
    if (tid < 128) {
        float s = 0.0f;
#pragma unroll
        for (int g = 0; g < 8; ++g) s += sacc[g][tid];
        atomicAdd(&stats[tid], s);
    }
}

// ---------------------------------------------------------------------------
// Kernel E: BN (batch stats) + LeakyReLU(0.1), in-place on out. (unchanged)
// ---------------------------------------------------------------------------
__global__ __launch_bounds__(256) void bn_leaky(float* __restrict__ out,
                                                const float* __restrict__ stats,
                                                const float* __restrict__ gamma,
                                                const float* __restrict__ beta) {
    int i = blockIdx.x * 256 + threadIdx.x;      // float4 index
    int oc = (i >> 14) & 63;
    float mean = stats[oc] * (1.0f / CNT_F);
    float var = stats[64 + oc] * (1.0f / CNT_F) - mean * mean;
    float scale = gamma[oc] * rsqrtf(var + 1e-5f);
    float shift = beta[oc] - mean * scale;
    float4* o4 = (float4*)out;
    float4 v = o4[i];
    v.x = v.x * scale + shift; v.x = v.x > 0.0f ? v.x : 0.1f * v.x;
    v.y = v.y * scale + shift; v.y = v.y > 0.0f ? v.y : 0.1f * v.y;
    v.z = v.z * scale + shift; v.z = v.z > 0.0f ? v.z : 0.1f * v.z;
    v.w = v.w * scale + shift; v.w = v.w > 0.0f ? v.w : 0.1f * v.w;
    o4[i] = v;
}

// ---------------------------------------------------------------------------
extern "C" void kernel_launch(void* const* d_in, const int* in_sizes, int n_in,
                              void* d_out, int out_size, void* d_ws, size_t ws_size,
                              hipStream_t stream) {
    (void)in_sizes; (void)n_in; (void)out_size; (void)ws_size;
    const float* x     = (const float*)d_in[0];
    const float* pw    = (const float*)d_in[1];
    const float* pb    = (const float*)d_in[2];
    const float* cw    = (const float*)d_in[3];
    const float* gamma = (const float*)d_in[4];
    const float* beta  = (const float*)d_in[5];
    float* out = (float*)d_out;
    char* ws = (char*)d_ws;

    __bf16* xtb  = (__bf16*)ws;                       // 34,080,768 B
    float* partials = (float*)(ws + 34080768);        // 8,388,608 B (old off region)
    __bf16* wtb  = (__bf16*)(ws + 34080768 + 18874368);            // 73,728 B
    __bf16* pwb  = (__bf16*)(ws + 34080768 + 18874368 + 73728);    // 36,864 B
    float*  stats = (float*)(ws + 34080768 + 18874368 + 73728 + 36864);

    prep<<<5341, 256, 0, stream>>>(x, xtb, cw, pw, wtb, pwb, stats);
    deform_fused<<<16384, 256, 0, stream>>>(xtb, pwb, pb, wtb, out, partials);
    stats_reduce<<<64, 256, 0, stream>>>(partials, stats);
    bn_leaky<<<NPIX * OCC / 4 / 256, 256, 0, stream>>>(out, stats, gamma, beta);
}